// Round 2
// baseline (580.883 us; speedup 1.0000x reference)
//
#include <hip/hip_runtime.h>

typedef __bf16 bf16;
typedef __attribute__((ext_vector_type(8))) __bf16 bf16x8;
typedef __attribute__((ext_vector_type(4))) float f32x4;

typedef __attribute__((address_space(1))) void gvoid_t;
typedef __attribute__((address_space(3))) void lvoid_t;

#define LDS_LOAD16(gp, lp) \
    __builtin_amdgcn_global_load_lds((gvoid_t*)(gp), (lvoid_t*)(lp), 16, 0, 0)

// ---------------------------------------------------------------------------
// fp32 -> bf16 conversion, 8 elems/thread (two float4 loads, one 16B store).
// ---------------------------------------------------------------------------
__global__ __launch_bounds__(256)
void f32_to_bf16(const float* __restrict__ in, bf16* __restrict__ out, int n8)
{
    const int i = blockIdx.x * 256 + threadIdx.x;
    if (i >= n8) return;
    const float4 a = ((const float4*)in)[i * 2];
    const float4 b = ((const float4*)in)[i * 2 + 1];
    bf16x8 o;
    o[0] = (bf16)a.x; o[1] = (bf16)a.y; o[2] = (bf16)a.z; o[3] = (bf16)a.w;
    o[4] = (bf16)b.x; o[5] = (bf16)b.y; o[6] = (bf16)b.z; o[7] = (bf16)b.w;
    *(bf16x8*)(out + (size_t)i * 8) = o;
}

// ---------------------------------------------------------------------------
// Legacy 128x128 GEMM (kept for proj + fallback path).
// C[m][n] = A[m][K] * B[n][K]^T (+ bias[n] if BIAS). bf16 in, fp32 accum.
// ---------------------------------------------------------------------------
template <int BIAS, typename CT>
__global__ __launch_bounds__(256, 2)
void gemm_bt(const bf16* __restrict__ A, const bf16* __restrict__ B,
             const float* __restrict__ bias, CT* __restrict__ C,
             int K, int ldc)
{
    __shared__ bf16 sA[128 * 32];
    __shared__ bf16 sB[128 * 32];
    const int tid  = threadIdx.x;
    const int lane = tid & 63;
    const int wid  = tid >> 6;
    const int m0 = blockIdx.y * 128;
    const int n0 = blockIdx.x * 128;
    const int wm = (wid >> 1) * 64;
    const int wn = (wid & 1) * 64;
    const int l15   = lane & 15;
    const int quad8 = (lane >> 4) * 8;

    f32x4 acc[4][4] = {};

    for (int k0 = 0; k0 < K; k0 += 32) {
#pragma unroll
        for (int t = 0; t < 2; ++t) {
            const int e  = (t * 4 + wid) * 512;   // wave-uniform LDS chunk base (elems)
            const int ge = e + lane * 8;
            const int r = ge >> 5, c = ge & 31;
            LDS_LOAD16(A + (size_t)(m0 + r) * K + k0 + c, sA + e);
            LDS_LOAD16(B + (size_t)(n0 + r) * K + k0 + c, sB + e);
        }
        __syncthreads();

        bf16x8 af[4], bfr[4];
#pragma unroll
        for (int i = 0; i < 4; ++i) {
            af[i]  = *(const bf16x8*)(sA + (wm + i * 16 + l15) * 32 + quad8);
            bfr[i] = *(const bf16x8*)(sB + (wn + i * 16 + l15) * 32 + quad8);
        }
#pragma unroll
        for (int i = 0; i < 4; ++i)
#pragma unroll
            for (int j = 0; j < 4; ++j)
                acc[i][j] = __builtin_amdgcn_mfma_f32_16x16x32_bf16(af[i], bfr[j], acc[i][j], 0, 0, 0);
        __syncthreads();
    }

    const int rowBase = m0 + wm + (lane >> 4) * 4;
    const int colBase = n0 + wn + l15;
#pragma unroll
    for (int j = 0; j < 4; ++j) {
        const int col = colBase + j * 16;
        const float bv = BIAS ? bias[col] : 0.0f;
#pragma unroll
        for (int i = 0; i < 4; ++i) {
            const int row = rowBase + i * 16;
#pragma unroll
            for (int r = 0; r < 4; ++r)
                C[(size_t)(row + r) * ldc + col] = (CT)(acc[i][j][r] + bv);
        }
    }
}

// ---------------------------------------------------------------------------
// 8-phase 256x192 GEMM, triple-buffered A / double-buffered B.
//  C[m][n] = A[m][K] * B[n][K]^T (+bias). bf16 in, fp32 accum, CT out.
//  - 512 threads = 8 waves (2M x 4N); per-wave output 128x48 (8x3 frags).
//  - BK=64. LDS 144 KiB: A 3 bufs (prefetch 2 tiles ahead), B 2 bufs.
//    XOR-swizzle both-sides (pre-swizzled global source + linear gload_lds
//    dest + XOR'd ds_read) -> conflict-free b128 reads (verified: 0 conflicts).
//  - Stage map per 8-phase iter (computes tiles u,u+1):
//      ph1-2: A(u+2)->bufA[a2]   ph3-4: B(u+2)->bufB0   [vmcnt(7)]
//      ph5-6: A(u+3)->bufA[a0]   ph7-8: B(u+3)->bufB1   [vmcnt(7)]
//    Every load has >=5 phases in flight (covers HBM latency); vmcnt(7)
//    retires exactly through the next-needed tile, never drains to 0.
//  - A-buffer rotation has period 3 iterations -> outer loop of 3 ITERs
//    with compile-time buffer indices. Requires NT = K/64 divisible by 6.
//  - Tail: stage k-tile clamped to NT-1 into never-read-again regions so
//    per-wave vmcnt counts stay exact.
//  Requires M%256==0, N%192==0, K%384==0.
// ---------------------------------------------------------------------------
template <int BIAS, typename CT>
__global__ __launch_bounds__(512, 2)
void gemm256_bt(const bf16* __restrict__ A, const bf16* __restrict__ B,
                const float* __restrict__ bias, CT* __restrict__ C,
                int K, int ldc)
{
    __shared__ bf16 sA[3 * 256 * 64];   // 96 KiB, buffers of 16384 elems
    __shared__ bf16 sB[2 * 192 * 64];   // 48 KiB, buffers of 12288 elems

    const int tid  = threadIdx.x;
    const int lane = tid & 63;
    const int wid  = tid >> 6;
    const int m0 = blockIdx.y * 256;
    const int n0 = blockIdx.x * 192;
    const int wm = (wid >> 2) * 128;        // 0 / 128
    const int wn = (wid & 3) * 48;          // 0 / 48 / 96 / 144  (all %8==0)
    const int l15  = lane & 15;
    const int quad = lane >> 4;
    const int swz  = l15 & 7;

    // ---- fixed per-thread staging offsets (source pre-swizzled, dest linear)
    int aoff[4], boff[3];
    int adst[4], bdst[3];
#pragma unroll
    for (int t = 0; t < 4; ++t) {
        const int slot = t * 512 + tid;       // A tile: 2048 slots of 8 elems
        const int r  = slot >> 3;             // row 0..255
        const int cg = (slot & 7) ^ (r & 7);  // global colgroup (inverse-swz)
        aoff[t] = (m0 + r) * K + cg * 8;
        adst[t] = (t * 512 + wid * 64) * 8;   // wave-uniform LDS base (elems)
    }
#pragma unroll
    for (int t = 0; t < 3; ++t) {
        const int slot = t * 512 + tid;       // B tile: 1536 slots
        const int r  = slot >> 3;             // row 0..191
        const int cg = (slot & 7) ^ (r & 7);
        boff[t] = (n0 + r) * K + cg * 8;
        bdst[t] = (t * 512 + wid * 64) * 8;
    }

#define STA(t, kt, buf) LDS_LOAD16(A + (size_t)aoff[t] + (kt) * 64, sA + (buf) * 16384 + adst[t])
#define STB(t, kt, buf) LDS_LOAD16(B + (size_t)boff[t] + (kt) * 64, sB + (buf) * 12288 + bdst[t])

    // ---- ds_read byte offsets per ksub (row&7 == l15&7 for all frag rows)
    int aRd[2], bRd[2];
#pragma unroll
    for (int kk = 0; kk < 2; ++kk) {
        const int pcg = (kk * 4 + quad) ^ swz;
        aRd[kk] = (wm + l15) * 128 + pcg * 16;
        bRd[kk] = (wn + l15) * 128 + pcg * 16;
    }

    f32x4 acc[8][3] = {};
    bf16x8 bfrag[3][2];   // B frags cached across a group's 4 phases

    // ---- prologue: issue tiles 0 and 1 (7 loads each); retire tile 0,
    //      keep tile 1's 7 loads in flight.
#pragma unroll
    for (int t = 0; t < 4; ++t) STA(t, 0, 0);
#pragma unroll
    for (int t = 0; t < 3; ++t) STB(t, 0, 0);
#pragma unroll
    for (int t = 0; t < 4; ++t) STA(t, 1, 1);
#pragma unroll
    for (int t = 0; t < 3; ++t) STB(t, 1, 1);
    asm volatile("s_waitcnt vmcnt(7)" ::: "memory");
    __builtin_amdgcn_s_barrier();

    // One phase: ds_read frag subtile (+B on p==0) | stage | bar | lgkm |
    //            setprio(1) 12xMFMA setprio(0) | [vmcnt] | bar
#define GRP_PHASE(p, ab, bb, STAGE_STMT, WAITC)                                     \
    {                                                                               \
        bf16x8 af[2][2];                                                            \
        _Pragma("unroll")                                                           \
        for (int mi = 0; mi < 2; ++mi)                                              \
            _Pragma("unroll")                                                       \
            for (int kk = 0; kk < 2; ++kk)                                          \
                af[mi][kk] = *(const bf16x8*)((const char*)sA + (ab) * 32768 +      \
                                              aRd[kk] + ((p) * 2 + mi) * 2048);     \
        if ((p) == 0) {                                                             \
            _Pragma("unroll")                                                       \
            for (int nf = 0; nf < 3; ++nf)                                          \
                _Pragma("unroll")                                                   \
                for (int kk = 0; kk < 2; ++kk)                                      \
                    bfrag[nf][kk] = *(const bf16x8*)((const char*)sB + (bb) * 24576 \
                                                     + bRd[kk] + nf * 2048);        \
        }                                                                           \
        STAGE_STMT;                                                                 \
        __builtin_amdgcn_s_barrier();                                               \
        asm volatile("s_waitcnt lgkmcnt(0)" ::: "memory");                          \
        __builtin_amdgcn_sched_barrier(0);                                          \
        __builtin_amdgcn_s_setprio(1);                                              \
        _Pragma("unroll")                                                           \
        for (int mi = 0; mi < 2; ++mi)                                              \
            _Pragma("unroll")                                                       \
            for (int nf = 0; nf < 3; ++nf)                                          \
                _Pragma("unroll")                                                   \
                for (int kk = 0; kk < 2; ++kk)                                      \
                    acc[(p) * 2 + mi][nf] = __builtin_amdgcn_mfma_f32_16x16x32_bf16(\
                        af[mi][kk], bfrag[nf][kk], acc[(p) * 2 + mi][kk == 0 ? nf : nf], 0, 0, 0); \
        __builtin_amdgcn_s_setprio(0);                                              \
        __builtin_amdgcn_sched_barrier(0);                                          \
        WAITC;                                                                      \
        __builtin_amdgcn_s_barrier();                                               \
    }

#define VM7 asm volatile("s_waitcnt vmcnt(7)" ::: "memory")

    // One iteration: compute tile u from bufA[A0i]/bufB0 (phases 1-4) and
    // tile u+1 from bufA[A1i]/bufB1 (phases 5-8). Stage A two tiles ahead.
#define ITER(u, A0i, A1i, A2i)                                               \
    {                                                                        \
        const int ke = ((u) + 2 < NT) ? (u) + 2 : NT - 1;                    \
        const int ko = ((u) + 3 < NT) ? (u) + 3 : NT - 1;                    \
        GRP_PHASE(0, A0i, 0, { STA(0, ke, A2i); STA(1, ke, A2i); }, )        \
        GRP_PHASE(1, A0i, 0, { STA(2, ke, A2i); STA(3, ke, A2i); }, )        \
        GRP_PHASE(2, A0i, 0, { STB(0, ke, 0); }, )                           \
        GRP_PHASE(3, A0i, 0, { STB(1, ke, 0); STB(2, ke, 0); }, VM7)         \
        GRP_PHASE(0, A1i, 1, { STA(0, ko, A0i); STA(1, ko, A0i); }, )        \
        GRP_PHASE(1, A1i, 1, { STA(2, ko, A0i); STA(3, ko, A0i); }, )        \
        GRP_PHASE(2, A1i, 1, { STB(0, ko, 1); }, )                           \
        GRP_PHASE(3, A1i, 1, { STB(1, ko, 1); STB(2, ko, 1); }, VM7)         \
    }

    const int NT = K >> 6;     // K-tiles of 64 (48 here; must be %6==0)
#pragma unroll 1
    for (int u6 = 0; u6 < NT; u6 += 6) {
        ITER(u6 + 0, 0, 1, 2)
        ITER(u6 + 2, 2, 0, 1)
        ITER(u6 + 4, 1, 2, 0)
    }
#undef ITER
#undef VM7
#undef GRP_PHASE
#undef STA
#undef STB

    asm volatile("s_waitcnt vmcnt(0)" ::: "memory");   // drain leftover DMA

    const int rowBase = m0 + wm + quad * 4;
    const int colBase = n0 + wn + l15;
#pragma unroll
    for (int nf = 0; nf < 3; ++nf) {
        const int col = colBase + nf * 16;
        const float bv = BIAS ? bias[col] : 0.0f;
#pragma unroll
        for (int mf = 0; mf < 8; ++mf) {
            const int row = rowBase + mf * 16;
#pragma unroll
            for (int r = 0; r < 4; ++r)
                C[(size_t)(row + r) * ldc + col] = (CT)(acc[mf][nf][r] + bv);
        }
    }
}

// ---------------------------------------------------------------------------
// QKNorm (fp32 RMS over head_dim=128) + RoPE + rearrange.
//  qkv [L][9216] bf16 -> Qh/Kh [24][2048][128] (normed+roped), Vt [24][128][2048].
// ---------------------------------------------------------------------------
__global__ __launch_bounds__(256)
void qk_rope_rearrange(const bf16* __restrict__ qkv, const float* __restrict__ pe,
                       const float* __restrict__ qs, const float* __restrict__ ks,
                       bf16* __restrict__ Qh, bf16* __restrict__ Kh, bf16* __restrict__ Vt)
{
    const int lane = threadIdx.x & 63;
    const int wid  = threadIdx.x >> 6;
    const int idx  = blockIdx.x * 4 + wid;     // = h*2048 + l
    const int h = idx >> 11;
    const int l = idx & 2047;

    const size_t rowb = (size_t)l * 9216 + h * 128 + 2 * lane;
    const float q0 = (float)qkv[rowb];
    const float q1 = (float)qkv[rowb + 1];
    const float k0 = (float)qkv[rowb + 3072];
    const float k1 = (float)qkv[rowb + 3073];
    const bf16  v0 = qkv[rowb + 6144];
    const bf16  v1 = qkv[rowb + 6145];

    float ssq = q0 * q0 + q1 * q1;
    float ssk = k0 * k0 + k1 * k1;
#pragma unroll
    for (int off = 1; off < 64; off <<= 1) {
        ssq += __shfl_xor(ssq, off);
        ssk += __shfl_xor(ssk, off);
    }
    const float rq = rsqrtf(ssq * (1.0f / 128.0f) + 1e-6f);
    const float rk = rsqrtf(ssk * (1.0f / 128.0f) + 1e-6f);

    const float s0q = qs[2 * lane], s1q = qs[2 * lane + 1];
    const float s0k = ks[2 * lane], s1k = ks[2 * lane + 1];

    const float qn0 = (q0 * rq) * s0q;
    const float qn1 = (q1 * rq) * s1q;
    const float kn0 = (k0 * rk) * s0k;
    const float kn1 = (k1 * rk) * s1k;

    const float* pp = pe + ((size_t)l * 64 + lane) * 4;
    const float p00 = pp[0], p01 = pp[1];
    const float p10 = pp[2], p11 = pp[3];

    const bf16 qo0 = (bf16)(p00 * qn0 + p01 * qn1);
    const bf16 qo1 = (bf16)(p10 * qn0 + p11 * qn1);
    const bf16 ko0 = (bf16)(p00 * kn0 + p01 * kn1);
    const bf16 ko1 = (bf16)(p10 * kn0 + p11 * kn1);

    const size_t ob = ((size_t)h * 2048 + l) * 128 + 2 * lane;
    Qh[ob] = qo0; Qh[ob + 1] = qo1;
    Kh[ob] = ko0; Kh[ob + 1] = ko1;

    const size_t vb = ((size_t)h * 128 + 2 * lane) * 2048 + l;
    Vt[vb]        = v0;
    Vt[vb + 2048] = v1;
}

// ---------------------------------------------------------------------------
// Flash attention v3. Block = 4 waves x 16 q-rows = 64 q; kv-steps of 64.
//  - K AND V staged via async global_load_lds into XOR-swizzled LDS tiles
//    (phys colgroup = logical ^ (row&7)); b128 reads 2-way aliased (free).
//  - Both double-buffered -> ONE barrier per step; DMA for step s+1 issued
//    right after barrier s, overlapping the whole compute phase.
//  - No-max softmax: p = exp(s/sqrt(d)); row-sum via 2 MFMAs vs ones.
// ---------------------------------------------------------------------------
__global__ __launch_bounds__(256, 2)
void flash_attn(const bf16* __restrict__ Qh, const bf16* __restrict__ Kh,
                const bf16* __restrict__ Vt, bf16* __restrict__ AO)
{
    __shared__ bf16 sK[2 * 64 * 128];  // [kv][d] swizzled, dbuf, 32 KB
    __shared__ bf16 sV[2 * 128 * 64];  // [d][kv] swizzled, dbuf, 32 KB
    __shared__ bf16 sP[4 * 16 * 72];   // per-wave P [q][kv], stride 72

    const int tid   = threadIdx.x;
    const int lane  = tid & 63;
    const int wid   = tid >> 6;
    const int h     = blockIdx.y;
    const int qw    = blockIdx.x * 64 + wid * 16;
    const int l15   = lane & 15;
    const int quad  = lane >> 4;
    const int quad8 = quad * 8;

    const bf16* Kbase = Kh + (size_t)h * 2048 * 128;
    const bf16* Vbase = Vt + (size_t)h * 128 * 2048;

    // Q fragments (A-layout) in registers
    bf16x8 aq[4];
    {
        const bf16* qp = Qh + ((size_t)h * 2048 + qw + l15) * 128 + quad8;
#pragma unroll
        for (int ki = 0; ki < 4; ++ki) aq[ki] = *(const bf16x8*)(qp + ki * 32);
    }

    bf16x8 ones;
#pragma unroll
    for (int i = 0; i < 8; ++i) ones[i] = (bf16)1.0f;

    f32x4 o[8] = {};
    f32x4 lacc = {};

    bf16* sPw = sP + wid * (16 * 72);
    const int slotbase = wid * 64;     // per-wave slot base (wave-uniform)

    // K tile: 64 kv-rows x 128 d. slot -> (r = slot>>4, pcg = slot&15),
    // global colgroup = pcg ^ (r&7)  (8-elem groups; only low 3 bits flip).
#define STAGE_K(kv, buf)                                                         \
    {                                                                            \
        bf16* kb = sK + (buf) * (64 * 128);                                      \
        _Pragma("unroll")                                                        \
        for (int t = 0; t < 4; ++t) {                                            \
            const int sb   = t * 256 + slotbase;                                 \
            const int slot = sb + lane;                                          \
            const int r    = slot >> 4;                                          \
            const int cg   = (slot & 15) ^ (r & 7);                              \
            LDS_LOAD16(Kbase + (size_t)((kv) + r) * 128 + cg * 8, kb + sb * 8);  \
        }                                                                        \
    }
    // V tile: 128 d-rows x 64 kv. slot -> (r = slot>>3, pcg = slot&7),
    // global colgroup = pcg ^ (r&7).
#define STAGE_V(kv, buf)                                                         \
    {                                                                            \
        bf16* vb = sV + (buf) * (128 * 64);                                      \
        _Pragma("unroll")                                                        \
        for (int t = 0; t < 4; ++t) {                                            \
            const int sb   = t * 256 + slotbase;                                 \
            const int slot = sb + lane;                                          \
            const int r    = slot >> 3;                                          \
            const int cg   = (slot & 7) ^ (r & 7);                               \
            LDS_LOAD16(Vbase + (size_t)r * 2048 + (kv) + cg * 8, vb + sb * 8);   \
        }                                                                        \
    }

    STAGE_K(0, 0);
    STAGE_V(0, 0);

    for (int s = 0; s < 32; ++s) {
        __syncthreads();                   // drains DMA for step s, syncs buffers
        if (s < 31) {                      // prefetch step s+1 into the other buffer
            STAGE_K((s + 1) * 64, (s + 1) & 1);
            STAGE_V((s + 1) * 64, (s + 1) & 1);
        }

        const bf16* kb = sK + (s & 1) * (64 * 128);
        const bf16* vb = sV + (s & 1) * (128 * 64);

        // S = Q K^T  (16 MFMA), swizzled sK reads
        f32x4 sc[4];
#pragma unroll
        for (int nt = 0; nt < 4; ++nt) {
            f32x4 t = {};
            const int row = nt * 16 + l15;
#pragma unroll
            for (int ki = 0; ki < 4; ++ki) {
                const int pcg = (4 * ki + quad) ^ (l15 & 7);
                bf16x8 bk = *(const bf16x8*)(kb + row * 128 + pcg * 8);
                t = __builtin_amdgcn_mfma_f32_16x16x32_bf16(aq[ki], bk, t, 0, 0, 0);
            }
            sc[nt] = t;
        }

        // p = exp(s * scale); write P to LDS (C-layout -> A-layout transform)
#pragma unroll
        for (int r = 0; r < 4; ++r) {
            const float scl = 0.08838834764831845f;   // 1/sqrt(128)
            bf16* pw = sPw + (quad * 4 + r) * 72 + l15;
            pw[0]  = (bf16)__expf(sc[0][r] * scl);
            pw[16] = (bf16)__expf(sc[1][r] * scl);
            pw[32] = (bf16)__expf(sc[2][r] * scl);
            pw[48] = (bf16)__expf(sc[3][r] * scl);
        }

        // PV (16 MFMA, V from swizzled sV) + row-sum l (2 MFMA vs ones)
#pragma unroll
        for (int kk = 0; kk < 2; ++kk) {
            bf16x8 pa = *(const bf16x8*)(sPw + l15 * 72 + kk * 32 + quad8);
            lacc = __builtin_amdgcn_mfma_f32_16x16x32_bf16(pa, ones, lacc, 0, 0, 0);
#pragma unroll
            for (int dt = 0; dt < 8; ++dt) {
                const int row = dt * 16 + l15;
                const int pcg = (kk * 4 + quad) ^ (l15 & 7);
                bf16x8 bv = *(const bf16x8*)(vb + row * 64 + pcg * 8);
                o[dt] = __builtin_amdgcn_mfma_f32_16x16x32_bf16(pa, bv, o[dt], 0, 0, 0);
            }
        }
    }
#undef STAGE_K
#undef STAGE_V

#pragma unroll
    for (int r = 0; r < 4; ++r) {
        const float inv = 1.0f / lacc[r];
        const size_t row = qw + quad * 4 + r;
        bf16* op = AO + row * 3072 + h * 128 + l15;
#pragma unroll
        for (int dt = 0; dt < 8; ++dt) op[dt * 16] = (bf16)(o[dt][r] * inv);
    }
}

// ---------------------------------------------------------------------------
extern "C" void kernel_launch(void* const* d_in, const int* in_sizes, int n_in,
                              void* d_out, int out_size, void* d_ws, size_t ws_size,
                              hipStream_t stream)
{
    (void)in_sizes; (void)n_in; (void)out_size;

    const float* x      = (const float*)d_in[0];
    const float* pe     = (const float*)d_in[1];
    const float* w_qkv  = (const float*)d_in[2];
    const float* w_proj = (const float*)d_in[3];
    const float* b_proj = (const float*)d_in[4];
    const float* q_s    = (const float*)d_in[5];
    const float* k_s    = (const float*)d_in[6];
    float* out = (float*)d_out;

    const size_t NEED_BIG = ((size_t)6291456 + 28311552 + 18874368 + 6291456) * 2; // 119.5 MB

    if (ws_size >= NEED_BIG) {
        // single-launch QKV path
        bf16* xb  = (bf16*)d_ws;                  //  6291456  x bf16
        bf16* wb  = xb + (size_t)6291456;         // 28311552  w_qkv bf16
        bf16* qkv = wb + (size_t)28311552;        // 18874368  [2048][9216]
        bf16* Vt  = qkv + (size_t)18874368;       //  6291456  [24][128][2048]
        bf16* Qh  = xb;                           // alias after GEMM
        bf16* Kh  = wb;                           // alias after GEMM
        bf16* wpb = qkv;                          // alias after rearrange
        bf16* AO  = qkv + (size_t)9437184;

        f32_to_bf16<<<dim3(3072),  256, 0, stream>>>(x,     xb, 786432);
        f32_to_bf16<<<dim3(13824), 256, 0, stream>>>(w_qkv, wb, 3538944);
        // 8-phase 256x192 GEMM: grid 48x8 = 384 blocks
        gemm256_bt<0, bf16><<<dim3(48, 8), 512, 0, stream>>>(xb, wb, nullptr, qkv, 3072, 9216);
        qk_rope_rearrange<<<dim3(12288), 256, 0, stream>>>(qkv, pe, q_s, k_s, Qh, Kh, Vt);
        f32_to_bf16<<<dim3(4608), 256, 0, stream>>>(w_proj, wpb, 1179648);
        flash_attn<<<dim3(32, 24), 256, 0, stream>>>(Qh, Kh, Vt, AO);
        gemm_bt<1, float><<<dim3(24, 16), 256, 0, stream>>>(AO, wpb, b_proj, out, 3072, 3072);
    } else {
        // chunked fallback (78.6 MB peak)
        bf16* xb  = (bf16*)d_ws;
        bf16* wb  = xb + (size_t)6291456;
        bf16* qkv = wb + (size_t)9437184;
        bf16* Vt  = qkv + (size_t)18874368;
        bf16* Qh  = xb;
        bf16* Kh  = wb;
        bf16* wpb = qkv;
        bf16* AO  = qkv + (size_t)9437184;

        f32_to_bf16<<<dim3(3072), 256, 0, stream>>>(x, xb, 786432);
        for (int c = 0; c < 3; ++c) {
            f32_to_bf16<<<dim3(4608), 256, 0, stream>>>(w_qkv + (size_t)c * 9437184, wb, 1179648);
            gemm_bt<0, bf16><<<dim3(24, 16), 256, 0, stream>>>(xb, wb, nullptr, qkv + c * 3072, 3072, 9216);
        }
        qk_rope_rearrange<<<dim3(12288), 256, 0, stream>>>(qkv, pe, q_s, k_s, Qh, Kh, Vt);
        f32_to_bf16<<<dim3(4608), 256, 0, stream>>>(w_proj, wpb, 1179648);
        flash_attn<<<dim3(32, 24), 256, 0, stream>>>(Qh, Kh, Vt, AO);
        gemm_bt<1, float><<<dim3(24, 16), 256, 0, stream>>>(AO, wpb, b_proj, out, 3072, 3072);
    }
}

// Round 3
// 555.388 us; speedup vs baseline: 1.0459x; 1.0459x over previous
//
#include <hip/hip_runtime.h>

typedef __bf16 bf16;
typedef __attribute__((ext_vector_type(8))) __bf16 bf16x8;
typedef __attribute__((ext_vector_type(4))) float f32x4;

typedef __attribute__((address_space(1))) void gvoid_t;
typedef __attribute__((address_space(3))) void lvoid_t;

#define LDS_LOAD16(gp, lp) \
    __builtin_amdgcn_global_load_lds((gvoid_t*)(gp), (lvoid_t*)(lp), 16, 0, 0)

// ---------------------------------------------------------------------------
// fp32 -> bf16 conversion, 8 elems/thread (two float4 loads, one 16B store).
// ---------------------------------------------------------------------------
__global__ __launch_bounds__(256)
void f32_to_bf16(const float* __restrict__ in, bf16* __restrict__ out, int n8)
{
    const int i = blockIdx.x * 256 + threadIdx.x;
    if (i >= n8) return;
    const float4 a = ((const float4*)in)[i * 2];
    const float4 b = ((const float4*)in)[i * 2 + 1];
    bf16x8 o;
    o[0] = (bf16)a.x; o[1] = (bf16)a.y; o[2] = (bf16)a.z; o[3] = (bf16)a.w;
    o[4] = (bf16)b.x; o[5] = (bf16)b.y; o[6] = (bf16)b.z; o[7] = (bf16)b.w;
    *(bf16x8*)(out + (size_t)i * 8) = o;
}

// ---------------------------------------------------------------------------
// Legacy 128x128 GEMM (kept for proj + fallback path).
// C[m][n] = A[m][K] * B[n][K]^T (+ bias[n] if BIAS). bf16 in, fp32 accum.
// ---------------------------------------------------------------------------
template <int BIAS, typename CT>
__global__ __launch_bounds__(256, 2)
void gemm_bt(const bf16* __restrict__ A, const bf16* __restrict__ B,
             const float* __restrict__ bias, CT* __restrict__ C,
             int K, int ldc)
{
    __shared__ bf16 sA[128 * 32];
    __shared__ bf16 sB[128 * 32];
    const int tid  = threadIdx.x;
    const int lane = tid & 63;
    const int wid  = tid >> 6;
    const int m0 = blockIdx.y * 128;
    const int n0 = blockIdx.x * 128;
    const int wm = (wid >> 1) * 64;
    const int wn = (wid & 1) * 64;
    const int l15   = lane & 15;
    const int quad8 = (lane >> 4) * 8;

    f32x4 acc[4][4] = {};

    for (int k0 = 0; k0 < K; k0 += 32) {
#pragma unroll
        for (int t = 0; t < 2; ++t) {
            const int e  = (t * 4 + wid) * 512;   // wave-uniform LDS chunk base (elems)
            const int ge = e + lane * 8;
            const int r = ge >> 5, c = ge & 31;
            LDS_LOAD16(A + (size_t)(m0 + r) * K + k0 + c, sA + e);
            LDS_LOAD16(B + (size_t)(n0 + r) * K + k0 + c, sB + e);
        }
        __syncthreads();

        bf16x8 af[4], bfr[4];
#pragma unroll
        for (int i = 0; i < 4; ++i) {
            af[i]  = *(const bf16x8*)(sA + (wm + i * 16 + l15) * 32 + quad8);
            bfr[i] = *(const bf16x8*)(sB + (wn + i * 16 + l15) * 32 + quad8);
        }
#pragma unroll
        for (int i = 0; i < 4; ++i)
#pragma unroll
            for (int j = 0; j < 4; ++j)
                acc[i][j] = __builtin_amdgcn_mfma_f32_16x16x32_bf16(af[i], bfr[j], acc[i][j], 0, 0, 0);
        __syncthreads();
    }

    const int rowBase = m0 + wm + (lane >> 4) * 4;
    const int colBase = n0 + wn + l15;
#pragma unroll
    for (int j = 0; j < 4; ++j) {
        const int col = colBase + j * 16;
        const float bv = BIAS ? bias[col] : 0.0f;
#pragma unroll
        for (int i = 0; i < 4; ++i) {
            const int row = rowBase + i * 16;
#pragma unroll
            for (int r = 0; r < 4; ++r)
                C[(size_t)(row + r) * ldc + col] = (CT)(acc[i][j][r] + bv);
        }
    }
}

// ---------------------------------------------------------------------------
// 128x192 GEMM @ 2 blocks/CU (barrier-idle absorbed by co-resident block).
//  C[m][n] = A[m][K] * B[n][K]^T (+bias). bf16 in, fp32 accum, CT out.
//  - 512 threads = 8 waves (2M x 4N); per-wave output 64x48 (4x3 frags).
//  - BK=64, double-buffered XOR-swizzled LDS = exactly 80 KiB -> 2 blocks/CU
//    (16 waves/CU). Grid 768 blocks = exactly 3 per CU: perfect balance,
//    no grid tail (vs 256x192's 1.5-round 75% efficiency).
//  - ONE barrier per K-tile (flash_attn's proven dbuf pattern):
//      barrier; stage u+1 (5 gload_lds); ds_read 14 frags; lgkm(4);
//      setprio(1); 12 MFMA; lgkm(0); 12 MFMA; setprio(0); vmcnt(0)
//    The vmcnt(0) drain stalls THIS block only - the other block on the CU
//    keeps the MFMA pipe fed (m114 co-schedule), unlike the 1-block/CU
//    8-phase schedule where all waves idled together (round-1/2 lesson).
//  - Swizzle both-sides: pre-swizzled global source + linear gload_lds dest
//    + XOR'd ds_read (colgroup ^= row&7) -> 0 bank conflicts (verified r1).
//  - lgkmcnt(4) is safe: read issue order pinned by sched_barrier(0) between
//    groups (rule #18: every asm wait is followed by sched_barrier(0)).
//  Requires M%128==0, N%192==0, K%64==0.
// ---------------------------------------------------------------------------
template <int BIAS, typename CT>
__global__ __launch_bounds__(512, 4)
void gemm128_bt(const bf16* __restrict__ A, const bf16* __restrict__ B,
                const float* __restrict__ bias, CT* __restrict__ C,
                int K, int ldc)
{
    __shared__ bf16 sA[2 * 128 * 64];   // 32 KiB, buf = 8192 elems (16384 B)
    __shared__ bf16 sB[2 * 192 * 64];   // 48 KiB, buf = 12288 elems (24576 B)

    const int tid  = threadIdx.x;
    const int lane = tid & 63;
    const int wid  = tid >> 6;
    const int m0 = blockIdx.y * 128;
    const int n0 = blockIdx.x * 192;
    const int wm = (wid >> 2) * 64;         // 0 / 64
    const int wn = (wid & 3) * 48;          // 0 / 48 / 96 / 144  (all %8==0)
    const int l15  = lane & 15;
    const int quad = lane >> 4;

    // ---- fixed per-thread staging offsets (source pre-swizzled, dest linear)
    int aoff[2], boff[3];
    int adst[2], bdst[3];
#pragma unroll
    for (int t = 0; t < 2; ++t) {
        const int slot = t * 512 + tid;       // A tile: 1024 slots of 8 elems
        const int r  = slot >> 3;             // row 0..127
        const int cg = (slot & 7) ^ (r & 7);  // global colgroup (inverse-swz)
        aoff[t] = (m0 + r) * K + cg * 8;
        adst[t] = (t * 512 + wid * 64) * 8;   // wave-uniform LDS base (elems)
    }
#pragma unroll
    for (int t = 0; t < 3; ++t) {
        const int slot = t * 512 + tid;       // B tile: 1536 slots
        const int r  = slot >> 3;             // row 0..191
        const int cg = (slot & 7) ^ (r & 7);
        boff[t] = (n0 + r) * K + cg * 8;
        bdst[t] = (t * 512 + wid * 64) * 8;
    }

#define STA(t, kt, buf) LDS_LOAD16(A + (size_t)aoff[t] + (kt) * 64, sA + (buf) * 8192  + adst[t])
#define STB(t, kt, buf) LDS_LOAD16(B + (size_t)boff[t] + (kt) * 64, sB + (buf) * 12288 + bdst[t])

    // ---- ds_read byte offsets per ksub (row&7 == l15&7 for all frag rows)
    int aRd[2], bRd[2];
#pragma unroll
    for (int kk = 0; kk < 2; ++kk) {
        const int pcg = (kk * 4 + quad) ^ (l15 & 7);
        aRd[kk] = (wm + l15) * 128 + pcg * 16;
        bRd[kk] = (wn + l15) * 128 + pcg * 16;
    }

    f32x4 acc[4][3] = {};

    // ---- prologue: stage tile 0 into buf0, retire fully.
#pragma unroll
    for (int t = 0; t < 2; ++t) STA(t, 0, 0);
#pragma unroll
    for (int t = 0; t < 3; ++t) STB(t, 0, 0);
    asm volatile("s_waitcnt vmcnt(0)" ::: "memory");

    const int NT = K >> 6;     // K-tiles of 64
#pragma unroll 1
    for (int u = 0; u < NT; ++u) {
        const int b = u & 1;
        __builtin_amdgcn_s_barrier();          // buf b complete for all waves
        // stage tile u+1 into buf b^1 (DMA overlaps this tile's compute)
        if (u + 1 < NT) {
            STA(0, u + 1, b ^ 1); STA(1, u + 1, b ^ 1);
            STB(0, u + 1, b ^ 1); STB(1, u + 1, b ^ 1); STB(2, u + 1, b ^ 1);
        }
        __builtin_amdgcn_sched_barrier(0);

        // group 1 reads: af[0..1] (4) + all B frags (6) = 10 ds_read_b128
        bf16x8 af[4][2], bfr[3][2];
#pragma unroll
        for (int mi = 0; mi < 2; ++mi)
#pragma unroll
            for (int kk = 0; kk < 2; ++kk)
                af[mi][kk] = *(const bf16x8*)((const char*)sA + b * 16384 +
                                              aRd[kk] + mi * 2048);
#pragma unroll
        for (int nf = 0; nf < 3; ++nf)
#pragma unroll
            for (int kk = 0; kk < 2; ++kk)
                bfr[nf][kk] = *(const bf16x8*)((const char*)sB + b * 24576 +
                                               bRd[kk] + nf * 2048);
        __builtin_amdgcn_sched_barrier(0);     // pin issue order for lgkm(4)
        // group 2 reads: af[2..3] (4)
#pragma unroll
        for (int mi = 2; mi < 4; ++mi)
#pragma unroll
            for (int kk = 0; kk < 2; ++kk)
                af[mi][kk] = *(const bf16x8*)((const char*)sA + b * 16384 +
                                              aRd[kk] + mi * 2048);
        __builtin_amdgcn_sched_barrier(0);

        asm volatile("s_waitcnt lgkmcnt(4)" ::: "memory");   // group 1 done
        __builtin_amdgcn_sched_barrier(0);
        __builtin_amdgcn_s_setprio(1);
#pragma unroll
        for (int mi = 0; mi < 2; ++mi)
#pragma unroll
            for (int nf = 0; nf < 3; ++nf)
#pragma unroll
                for (int kk = 0; kk < 2; ++kk)
                    acc[mi][nf] = __builtin_amdgcn_mfma_f32_16x16x32_bf16(
                        af[mi][kk], bfr[nf][kk], acc[mi][nf], 0, 0, 0);
        __builtin_amdgcn_sched_barrier(0);
        asm volatile("s_waitcnt lgkmcnt(0)" ::: "memory");   // group 2 done
        __builtin_amdgcn_sched_barrier(0);
#pragma unroll
        for (int mi = 2; mi < 4; ++mi)
#pragma unroll
            for (int nf = 0; nf < 3; ++nf)
#pragma unroll
                for (int kk = 0; kk < 2; ++kk)
                    acc[mi][nf] = __builtin_amdgcn_mfma_f32_16x16x32_bf16(
                        af[mi][kk], bfr[nf][kk], acc[mi][nf], 0, 0, 0);
        __builtin_amdgcn_s_setprio(0);
        __builtin_amdgcn_sched_barrier(0);
        asm volatile("s_waitcnt vmcnt(0)" ::: "memory");     // tile u+1 DMA done
    }
#undef STA
#undef STB

    const int rowBase = m0 + wm + quad * 4;
    const int colBase = n0 + wn + l15;
#pragma unroll
    for (int nf = 0; nf < 3; ++nf) {
        const int col = colBase + nf * 16;
        const float bv = BIAS ? bias[col] : 0.0f;
#pragma unroll
        for (int mf = 0; mf < 4; ++mf) {
            const int row = rowBase + mf * 16;
#pragma unroll
            for (int r = 0; r < 4; ++r)
                C[(size_t)(row + r) * ldc + col] = (CT)(acc[mf][nf][r] + bv);
        }
    }
}

// ---------------------------------------------------------------------------
// QKNorm (fp32 RMS over head_dim=128) + RoPE + rearrange.
//  qkv [L][9216] bf16 -> Qh/Kh [24][2048][128] (normed+roped), Vt [24][128][2048].
// ---------------------------------------------------------------------------
__global__ __launch_bounds__(256)
void qk_rope_rearrange(const bf16* __restrict__ qkv, const float* __restrict__ pe,
                       const float* __restrict__ qs, const float* __restrict__ ks,
                       bf16* __restrict__ Qh, bf16* __restrict__ Kh, bf16* __restrict__ Vt)
{
    const int lane = threadIdx.x & 63;
    const int wid  = threadIdx.x >> 6;
    const int idx  = blockIdx.x * 4 + wid;     // = h*2048 + l
    const int h = idx >> 11;
    const int l = idx & 2047;

    const size_t rowb = (size_t)l * 9216 + h * 128 + 2 * lane;
    const float q0 = (float)qkv[rowb];
    const float q1 = (float)qkv[rowb + 1];
    const float k0 = (float)qkv[rowb + 3072];
    const float k1 = (float)qkv[rowb + 3073];
    const bf16  v0 = qkv[rowb + 6144];
    const bf16  v1 = qkv[rowb + 6145];

    float ssq = q0 * q0 + q1 * q1;
    float ssk = k0 * k0 + k1 * k1;
#pragma unroll
    for (int off = 1; off < 64; off <<= 1) {
        ssq += __shfl_xor(ssq, off);
        ssk += __shfl_xor(ssk, off);
    }
    const float rq = rsqrtf(ssq * (1.0f / 128.0f) + 1e-6f);
    const float rk = rsqrtf(ssk * (1.0f / 128.0f) + 1e-6f);

    const float s0q = qs[2 * lane], s1q = qs[2 * lane + 1];
    const float s0k = ks[2 * lane], s1k = ks[2 * lane + 1];

    const float qn0 = (q0 * rq) * s0q;
    const float qn1 = (q1 * rq) * s1q;
    const float kn0 = (k0 * rk) * s0k;
    const float kn1 = (k1 * rk) * s1k;

    const float* pp = pe + ((size_t)l * 64 + lane) * 4;
    const float p00 = pp[0], p01 = pp[1];
    const float p10 = pp[2], p11 = pp[3];

    const bf16 qo0 = (bf16)(p00 * qn0 + p01 * qn1);
    const bf16 qo1 = (bf16)(p10 * qn0 + p11 * qn1);
    const bf16 ko0 = (bf16)(p00 * kn0 + p01 * kn1);
    const bf16 ko1 = (bf16)(p10 * kn0 + p11 * kn1);

    const size_t ob = ((size_t)h * 2048 + l) * 128 + 2 * lane;
    Qh[ob] = qo0; Qh[ob + 1] = qo1;
    Kh[ob] = ko0; Kh[ob + 1] = ko1;

    const size_t vb = ((size_t)h * 128 + 2 * lane) * 2048 + l;
    Vt[vb]        = v0;
    Vt[vb + 2048] = v1;
}

// ---------------------------------------------------------------------------
// Flash attention v3. Block = 4 waves x 16 q-rows = 64 q; kv-steps of 64.
//  - K AND V staged via async global_load_lds into XOR-swizzled LDS tiles
//    (phys colgroup = logical ^ (row&7)); b128 reads 2-way aliased (free).
//  - Both double-buffered -> ONE barrier per step; DMA for step s+1 issued
//    right after barrier s, overlapping the whole compute phase.
//  - No-max softmax: p = exp(s/sqrt(d)); row-sum via 2 MFMAs vs ones.
// ---------------------------------------------------------------------------
__global__ __launch_bounds__(256, 2)
void flash_attn(const bf16* __restrict__ Qh, const bf16* __restrict__ Kh,
                const bf16* __restrict__ Vt, bf16* __restrict__ AO)
{
    __shared__ bf16 sK[2 * 64 * 128];  // [kv][d] swizzled, dbuf, 32 KB
    __shared__ bf16 sV[2 * 128 * 64];  // [d][kv] swizzled, dbuf, 32 KB
    __shared__ bf16 sP[4 * 16 * 72];   // per-wave P [q][kv], stride 72

    const int tid   = threadIdx.x;
    const int lane  = tid & 63;
    const int wid   = tid >> 6;
    const int h     = blockIdx.y;
    const int qw    = blockIdx.x * 64 + wid * 16;
    const int l15   = lane & 15;
    const int quad  = lane >> 4;
    const int quad8 = quad * 8;

    const bf16* Kbase = Kh + (size_t)h * 2048 * 128;
    const bf16* Vbase = Vt + (size_t)h * 128 * 2048;

    // Q fragments (A-layout) in registers
    bf16x8 aq[4];
    {
        const bf16* qp = Qh + ((size_t)h * 2048 + qw + l15) * 128 + quad8;
#pragma unroll
        for (int ki = 0; ki < 4; ++ki) aq[ki] = *(const bf16x8*)(qp + ki * 32);
    }

    bf16x8 ones;
#pragma unroll
    for (int i = 0; i < 8; ++i) ones[i] = (bf16)1.0f;

    f32x4 o[8] = {};
    f32x4 lacc = {};

    bf16* sPw = sP + wid * (16 * 72);
    const int slotbase = wid * 64;     // per-wave slot base (wave-uniform)

    // K tile: 64 kv-rows x 128 d. slot -> (r = slot>>4, pcg = slot&15),
    // global colgroup = pcg ^ (r&7)  (8-elem groups; only low 3 bits flip).
#define STAGE_K(kv, buf)                                                         \
    {                                                                            \
        bf16* kb = sK + (buf) * (64 * 128);                                      \
        _Pragma("unroll")                                                        \
        for (int t = 0; t < 4; ++t) {                                            \
            const int sb   = t * 256 + slotbase;                                 \
            const int slot = sb + lane;                                          \
            const int r    = slot >> 4;                                          \
            const int cg   = (slot & 15) ^ (r & 7);                              \
            LDS_LOAD16(Kbase + (size_t)((kv) + r) * 128 + cg * 8, kb + sb * 8);  \
        }                                                                        \
    }
    // V tile: 128 d-rows x 64 kv. slot -> (r = slot>>3, pcg = slot&7),
    // global colgroup = pcg ^ (r&7).
#define STAGE_V(kv, buf)                                                         \
    {                                                                            \
        bf16* vb = sV + (buf) * (128 * 64);                                      \
        _Pragma("unroll")                                                        \
        for (int t = 0; t < 4; ++t) {                                            \
            const int sb   = t * 256 + slotbase;                                 \
            const int slot = sb + lane;                                          \
            const int r    = slot >> 3;                                          \
            const int cg   = (slot & 7) ^ (r & 7);                               \
            LDS_LOAD16(Vbase + (size_t)r * 2048 + (kv) + cg * 8, vb + sb * 8);   \
        }                                                                        \
    }

    STAGE_K(0, 0);
    STAGE_V(0, 0);

    for (int s = 0; s < 32; ++s) {
        __syncthreads();                   // drains DMA for step s, syncs buffers
        if (s < 31) {                      // prefetch step s+1 into the other buffer
            STAGE_K((s + 1) * 64, (s + 1) & 1);
            STAGE_V((s + 1) * 64, (s + 1) & 1);
        }

        const bf16* kb = sK + (s & 1) * (64 * 128);
        const bf16* vb = sV + (s & 1) * (128 * 64);

        // S = Q K^T  (16 MFMA), swizzled sK reads
        f32x4 sc[4];
#pragma unroll
        for (int nt = 0; nt < 4; ++nt) {
            f32x4 t = {};
            const int row = nt * 16 + l15;
#pragma unroll
            for (int ki = 0; ki < 4; ++ki) {
                const int pcg = (4 * ki + quad) ^ (l15 & 7);
                bf16x8 bk = *(const bf16x8*)(kb + row * 128 + pcg * 8);
                t = __builtin_amdgcn_mfma_f32_16x16x32_bf16(aq[ki], bk, t, 0, 0, 0);
            }
            sc[nt] = t;
        }

        // p = exp(s * scale); write P to LDS (C-layout -> A-layout transform)
#pragma unroll
        for (int r = 0; r < 4; ++r) {
            const float scl = 0.08838834764831845f;   // 1/sqrt(128)
            bf16* pw = sPw + (quad * 4 + r) * 72 + l15;
            pw[0]  = (bf16)__expf(sc[0][r] * scl);
            pw[16] = (bf16)__expf(sc[1][r] * scl);
            pw[32] = (bf16)__expf(sc[2][r] * scl);
            pw[48] = (bf16)__expf(sc[3][r] * scl);
        }

        // PV (16 MFMA, V from swizzled sV) + row-sum l (2 MFMA vs ones)
#pragma unroll
        for (int kk = 0; kk < 2; ++kk) {
            bf16x8 pa = *(const bf16x8*)(sPw + l15 * 72 + kk * 32 + quad8);
            lacc = __builtin_amdgcn_mfma_f32_16x16x32_bf16(pa, ones, lacc, 0, 0, 0);
#pragma unroll
            for (int dt = 0; dt < 8; ++dt) {
                const int row = dt * 16 + l15;
                const int pcg = (kk * 4 + quad) ^ (l15 & 7);
                bf16x8 bv = *(const bf16x8*)(vb + row * 64 + pcg * 8);
                o[dt] = __builtin_amdgcn_mfma_f32_16x16x32_bf16(pa, bv, o[dt], 0, 0, 0);
            }
        }
    }
#undef STAGE_K
#undef STAGE_V

#pragma unroll
    for (int r = 0; r < 4; ++r) {
        const float inv = 1.0f / lacc[r];
        const size_t row = qw + quad * 4 + r;
        bf16* op = AO + row * 3072 + h * 128 + l15;
#pragma unroll
        for (int dt = 0; dt < 8; ++dt) op[dt * 16] = (bf16)(o[dt][r] * inv);
    }
}

// ---------------------------------------------------------------------------
extern "C" void kernel_launch(void* const* d_in, const int* in_sizes, int n_in,
                              void* d_out, int out_size, void* d_ws, size_t ws_size,
                              hipStream_t stream)
{
    (void)in_sizes; (void)n_in; (void)out_size;

    const float* x      = (const float*)d_in[0];
    const float* pe     = (const float*)d_in[1];
    const float* w_qkv  = (const float*)d_in[2];
    const float* w_proj = (const float*)d_in[3];
    const float* b_proj = (const float*)d_in[4];
    const float* q_s    = (const float*)d_in[5];
    const float* k_s    = (const float*)d_in[6];
    float* out = (float*)d_out;

    const size_t NEED_BIG = ((size_t)6291456 + 28311552 + 18874368 + 6291456) * 2; // 119.5 MB

    if (ws_size >= NEED_BIG) {
        // single-launch QKV path
        bf16* xb  = (bf16*)d_ws;                  //  6291456  x bf16
        bf16* wb  = xb + (size_t)6291456;         // 28311552  w_qkv bf16
        bf16* qkv = wb + (size_t)28311552;        // 18874368  [2048][9216]
        bf16* Vt  = qkv + (size_t)18874368;       //  6291456  [24][128][2048]
        bf16* Qh  = xb;                           // alias after GEMM
        bf16* Kh  = wb;                           // alias after GEMM
        bf16* wpb = qkv;                          // alias after rearrange
        bf16* AO  = qkv + (size_t)9437184;

        f32_to_bf16<<<dim3(3072),  256, 0, stream>>>(x,     xb, 786432);
        f32_to_bf16<<<dim3(13824), 256, 0, stream>>>(w_qkv, wb, 3538944);
        // 128x192 GEMM @ 2 blocks/CU: grid 48x16 = 768 blocks = exactly 3/CU
        gemm128_bt<0, bf16><<<dim3(48, 16), 512, 0, stream>>>(xb, wb, nullptr, qkv, 3072, 9216);
        qk_rope_rearrange<<<dim3(12288), 256, 0, stream>>>(qkv, pe, q_s, k_s, Qh, Kh, Vt);
        f32_to_bf16<<<dim3(4608), 256, 0, stream>>>(w_proj, wpb, 1179648);
        flash_attn<<<dim3(32, 24), 256, 0, stream>>>(Qh, Kh, Vt, AO);
        gemm_bt<1, float><<<dim3(24, 16), 256, 0, stream>>>(AO, wpb, b_proj, out, 3072, 3072);
    } else {
        // chunked fallback (78.6 MB peak)
        bf16* xb  = (bf16*)d_ws;
        bf16* wb  = xb + (size_t)6291456;
        bf16* qkv = wb + (size_t)9437184;
        bf16* Vt  = qkv + (size_t)18874368;
        bf16* Qh  = xb;
        bf16* Kh  = wb;
        bf16* wpb = qkv;
        bf16* AO  = qkv + (size_t)9437184;

        f32_to_bf16<<<dim3(3072), 256, 0, stream>>>(x, xb, 786432);
        for (int c = 0; c < 3; ++c) {
            f32_to_bf16<<<dim3(4608), 256, 0, stream>>>(w_qkv + (size_t)c * 9437184, wb, 1179648);
            gemm_bt<0, bf16><<<dim3(24, 16), 256, 0, stream>>>(xb, wb, nullptr, qkv + c * 3072, 3072, 9216);
        }
        qk_rope_rearrange<<<dim3(12288), 256, 0, stream>>>(qkv, pe, q_s, k_s, Qh, Kh, Vt);
        f32_to_bf16<<<dim3(4608), 256, 0, stream>>>(w_proj, wpb, 1179648);
        flash_attn<<<dim3(32, 24), 256, 0, stream>>>(Qh, Kh, Vt, AO);
        gemm_bt<1, float><<<dim3(24, 16), 256, 0, stream>>>(AO, wpb, b_proj, out, 3072, 3072);
    }
}

// Round 4
// 535.252 us; speedup vs baseline: 1.0853x; 1.0376x over previous
//
#include <hip/hip_runtime.h>

typedef __bf16 bf16;
typedef __attribute__((ext_vector_type(8))) __bf16 bf16x8;
typedef __attribute__((ext_vector_type(4))) float f32x4;

typedef __attribute__((address_space(1))) void gvoid_t;
typedef __attribute__((address_space(3))) void lvoid_t;

#define LDS_LOAD16(gp, lp) \
    __builtin_amdgcn_global_load_lds((gvoid_t*)(gp), (lvoid_t*)(lp), 16, 0, 0)

// ---------------------------------------------------------------------------
// fp32 -> bf16 conversion, 8 elems/thread (two float4 loads, one 16B store).
// ---------------------------------------------------------------------------
__global__ __launch_bounds__(256)
void f32_to_bf16(const float* __restrict__ in, bf16* __restrict__ out, int n8)
{
    const int i = blockIdx.x * 256 + threadIdx.x;
    if (i >= n8) return;
    const float4 a = ((const float4*)in)[i * 2];
    const float4 b = ((const float4*)in)[i * 2 + 1];
    bf16x8 o;
    o[0] = (bf16)a.x; o[1] = (bf16)a.y; o[2] = (bf16)a.z; o[3] = (bf16)a.w;
    o[4] = (bf16)b.x; o[5] = (bf16)b.y; o[6] = (bf16)b.z; o[7] = (bf16)b.w;
    *(bf16x8*)(out + (size_t)i * 8) = o;
}

// ---------------------------------------------------------------------------
// Legacy 128x128 GEMM (kept for chunked-fallback QKV path).
// ---------------------------------------------------------------------------
template <int BIAS, typename CT>
__global__ __launch_bounds__(256, 2)
void gemm_bt(const bf16* __restrict__ A, const bf16* __restrict__ B,
             const float* __restrict__ bias, CT* __restrict__ C,
             int K, int ldc)
{
    __shared__ bf16 sA[128 * 32];
    __shared__ bf16 sB[128 * 32];
    const int tid  = threadIdx.x;
    const int lane = tid & 63;
    const int wid  = tid >> 6;
    const int m0 = blockIdx.y * 128;
    const int n0 = blockIdx.x * 128;
    const int wm = (wid >> 1) * 64;
    const int wn = (wid & 1) * 64;
    const int l15   = lane & 15;
    const int quad8 = (lane >> 4) * 8;

    f32x4 acc[4][4] = {};

    for (int k0 = 0; k0 < K; k0 += 32) {
#pragma unroll
        for (int t = 0; t < 2; ++t) {
            const int e  = (t * 4 + wid) * 512;
            const int ge = e + lane * 8;
            const int r = ge >> 5, c = ge & 31;
            LDS_LOAD16(A + (size_t)(m0 + r) * K + k0 + c, sA + e);
            LDS_LOAD16(B + (size_t)(n0 + r) * K + k0 + c, sB + e);
        }
        __syncthreads();

        bf16x8 af[4], bfr[4];
#pragma unroll
        for (int i = 0; i < 4; ++i) {
            af[i]  = *(const bf16x8*)(sA + (wm + i * 16 + l15) * 32 + quad8);
            bfr[i] = *(const bf16x8*)(sB + (wn + i * 16 + l15) * 32 + quad8);
        }
#pragma unroll
        for (int i = 0; i < 4; ++i)
#pragma unroll
            for (int j = 0; j < 4; ++j)
                acc[i][j] = __builtin_amdgcn_mfma_f32_16x16x32_bf16(af[i], bfr[j], acc[i][j], 0, 0, 0);
        __syncthreads();
    }

    const int rowBase = m0 + wm + (lane >> 4) * 4;
    const int colBase = n0 + wn + l15;
#pragma unroll
    for (int j = 0; j < 4; ++j) {
        const int col = colBase + j * 16;
        const float bv = BIAS ? bias[col] : 0.0f;
#pragma unroll
        for (int i = 0; i < 4; ++i) {
            const int row = rowBase + i * 16;
#pragma unroll
            for (int r = 0; r < 4; ++r)
                C[(size_t)(row + r) * ldc + col] = (CT)(acc[i][j][r] + bv);
        }
    }
}

// ---------------------------------------------------------------------------
// 128x192 GEMM @ 2 blocks/CU (barrier-idle absorbed by co-resident block).
//  Proven round-3 structure: 932 TF on the QKV shape. See comments there.
// ---------------------------------------------------------------------------
template <int BIAS, typename CT>
__global__ __launch_bounds__(512, 4)
void gemm128_bt(const bf16* __restrict__ A, const bf16* __restrict__ B,
                const float* __restrict__ bias, CT* __restrict__ C,
                int K, int ldc)
{
    __shared__ bf16 sA[2 * 128 * 64];   // 32 KiB
    __shared__ bf16 sB[2 * 192 * 64];   // 48 KiB

    const int tid  = threadIdx.x;
    const int lane = tid & 63;
    const int wid  = tid >> 6;
    const int m0 = blockIdx.y * 128;
    const int n0 = blockIdx.x * 192;
    const int wm = (wid >> 2) * 64;
    const int wn = (wid & 3) * 48;
    const int l15  = lane & 15;
    const int quad = lane >> 4;

    int aoff[2], boff[3];
    int adst[2], bdst[3];
#pragma unroll
    for (int t = 0; t < 2; ++t) {
        const int slot = t * 512 + tid;
        const int r  = slot >> 3;
        const int cg = (slot & 7) ^ (r & 7);
        aoff[t] = (m0 + r) * K + cg * 8;
        adst[t] = (t * 512 + wid * 64) * 8;
    }
#pragma unroll
    for (int t = 0; t < 3; ++t) {
        const int slot = t * 512 + tid;
        const int r  = slot >> 3;
        const int cg = (slot & 7) ^ (r & 7);
        boff[t] = (n0 + r) * K + cg * 8;
        bdst[t] = (t * 512 + wid * 64) * 8;
    }

#define STA(t, kt, buf) LDS_LOAD16(A + (size_t)aoff[t] + (kt) * 64, sA + (buf) * 8192  + adst[t])
#define STB(t, kt, buf) LDS_LOAD16(B + (size_t)boff[t] + (kt) * 64, sB + (buf) * 12288 + bdst[t])

    int aRd[2], bRd[2];
#pragma unroll
    for (int kk = 0; kk < 2; ++kk) {
        const int pcg = (kk * 4 + quad) ^ (l15 & 7);
        aRd[kk] = (wm + l15) * 128 + pcg * 16;
        bRd[kk] = (wn + l15) * 128 + pcg * 16;
    }

    f32x4 acc[4][3] = {};

#pragma unroll
    for (int t = 0; t < 2; ++t) STA(t, 0, 0);
#pragma unroll
    for (int t = 0; t < 3; ++t) STB(t, 0, 0);
    asm volatile("s_waitcnt vmcnt(0)" ::: "memory");

    const int NT = K >> 6;
#pragma unroll 1
    for (int u = 0; u < NT; ++u) {
        const int b = u & 1;
        __builtin_amdgcn_s_barrier();
        if (u + 1 < NT) {
            STA(0, u + 1, b ^ 1); STA(1, u + 1, b ^ 1);
            STB(0, u + 1, b ^ 1); STB(1, u + 1, b ^ 1); STB(2, u + 1, b ^ 1);
        }
        __builtin_amdgcn_sched_barrier(0);

        bf16x8 af[4][2], bfr[3][2];
#pragma unroll
        for (int mi = 0; mi < 2; ++mi)
#pragma unroll
            for (int kk = 0; kk < 2; ++kk)
                af[mi][kk] = *(const bf16x8*)((const char*)sA + b * 16384 +
                                              aRd[kk] + mi * 2048);
#pragma unroll
        for (int nf = 0; nf < 3; ++nf)
#pragma unroll
            for (int kk = 0; kk < 2; ++kk)
                bfr[nf][kk] = *(const bf16x8*)((const char*)sB + b * 24576 +
                                               bRd[kk] + nf * 2048);
        __builtin_amdgcn_sched_barrier(0);
#pragma unroll
        for (int mi = 2; mi < 4; ++mi)
#pragma unroll
            for (int kk = 0; kk < 2; ++kk)
                af[mi][kk] = *(const bf16x8*)((const char*)sA + b * 16384 +
                                              aRd[kk] + mi * 2048);
        __builtin_amdgcn_sched_barrier(0);

        asm volatile("s_waitcnt lgkmcnt(4)" ::: "memory");
        __builtin_amdgcn_sched_barrier(0);
        __builtin_amdgcn_s_setprio(1);
#pragma unroll
        for (int mi = 0; mi < 2; ++mi)
#pragma unroll
            for (int nf = 0; nf < 3; ++nf)
#pragma unroll
                for (int kk = 0; kk < 2; ++kk)
                    acc[mi][nf] = __builtin_amdgcn_mfma_f32_16x16x32_bf16(
                        af[mi][kk], bfr[nf][kk], acc[mi][nf], 0, 0, 0);
        __builtin_amdgcn_sched_barrier(0);
        asm volatile("s_waitcnt lgkmcnt(0)" ::: "memory");
        __builtin_amdgcn_sched_barrier(0);
#pragma unroll
        for (int mi = 2; mi < 4; ++mi)
#pragma unroll
            for (int nf = 0; nf < 3; ++nf)
#pragma unroll
                for (int kk = 0; kk < 2; ++kk)
                    acc[mi][nf] = __builtin_amdgcn_mfma_f32_16x16x32_bf16(
                        af[mi][kk], bfr[nf][kk], acc[mi][nf], 0, 0, 0);
        __builtin_amdgcn_s_setprio(0);
        __builtin_amdgcn_sched_barrier(0);
        asm volatile("s_waitcnt vmcnt(0)" ::: "memory");
    }
#undef STA
#undef STB

    const int rowBase = m0 + wm + quad * 4;
    const int colBase = n0 + wn + l15;
#pragma unroll
    for (int nf = 0; nf < 3; ++nf) {
        const int col = colBase + nf * 16;
        const float bv = BIAS ? bias[col] : 0.0f;
#pragma unroll
        for (int mf = 0; mf < 4; ++mf) {
            const int row = rowBase + mf * 16;
#pragma unroll
            for (int r = 0; r < 4; ++r)
                C[(size_t)(row + r) * ldc + col] = (CT)(acc[mf][nf][r] + bv);
        }
    }
}

// ---------------------------------------------------------------------------
// 64x192 GEMM @ 2 blocks/CU for the proj shape (M=2048 -> grid 16x32 = 512
//  blocks = exactly 2/CU, perfectly balanced). Same proven schedule as
//  gemm128_bt; per-CU MFMA per K-tile identical (16 waves x 12 = 192).
//  8 waves = 2M x 4N; per-wave 32x48 (2x3 frags). LDS 64 KiB.
//  Requires M%64==0, N%192==0, K%64==0.
// ---------------------------------------------------------------------------
template <int BIAS, typename CT>
__global__ __launch_bounds__(512, 4)
void gemm64_bt(const bf16* __restrict__ A, const bf16* __restrict__ B,
               const float* __restrict__ bias, CT* __restrict__ C,
               int K, int ldc)
{
    __shared__ bf16 sA[2 * 64 * 64];    // 16 KiB, buf = 4096 elems
    __shared__ bf16 sB[2 * 192 * 64];   // 48 KiB, buf = 12288 elems

    const int tid  = threadIdx.x;
    const int lane = tid & 63;
    const int wid  = tid >> 6;
    const int m0 = blockIdx.y * 64;
    const int n0 = blockIdx.x * 192;
    const int wm = (wid >> 2) * 32;         // 0 / 32
    const int wn = (wid & 3) * 48;          // 0 / 48 / 96 / 144
    const int l15  = lane & 15;
    const int quad = lane >> 4;

    // A tile: 64x64 = 512 slots of 8 elems -> 1 load/thread.
    int aoff, adst;
    {
        const int slot = tid;
        const int r  = slot >> 3;             // row 0..63
        const int cg = (slot & 7) ^ (r & 7);
        aoff = (m0 + r) * K + cg * 8;
        adst = (wid * 64) * 8;                // wave-uniform base
    }
    int boff[3], bdst[3];
#pragma unroll
    for (int t = 0; t < 3; ++t) {
        const int slot = t * 512 + tid;       // B tile: 1536 slots
        const int r  = slot >> 3;
        const int cg = (slot & 7) ^ (r & 7);
        boff[t] = (n0 + r) * K + cg * 8;
        bdst[t] = (t * 512 + wid * 64) * 8;
    }

#define STA64(kt, buf)    LDS_LOAD16(A + (size_t)aoff    + (kt) * 64, sA + (buf) * 4096  + adst)
#define STB64(t, kt, buf) LDS_LOAD16(B + (size_t)boff[t] + (kt) * 64, sB + (buf) * 12288 + bdst[t])

    int aRd[2], bRd[2];
#pragma unroll
    for (int kk = 0; kk < 2; ++kk) {
        const int pcg = (kk * 4 + quad) ^ (l15 & 7);
        aRd[kk] = (wm + l15) * 128 + pcg * 16;
        bRd[kk] = (wn + l15) * 128 + pcg * 16;
    }

    f32x4 acc[2][3] = {};

    STA64(0, 0);
#pragma unroll
    for (int t = 0; t < 3; ++t) STB64(t, 0, 0);
    asm volatile("s_waitcnt vmcnt(0)" ::: "memory");

    const int NT = K >> 6;
#pragma unroll 1
    for (int u = 0; u < NT; ++u) {
        const int b = u & 1;
        __builtin_amdgcn_s_barrier();
        if (u + 1 < NT) {
            STA64(u + 1, b ^ 1);
            STB64(0, u + 1, b ^ 1); STB64(1, u + 1, b ^ 1); STB64(2, u + 1, b ^ 1);
        }
        __builtin_amdgcn_sched_barrier(0);

        // group 1 reads: af[0] (2) + all B frags (6) = 8 ds_read_b128
        bf16x8 af[2][2], bfr[3][2];
#pragma unroll
        for (int kk = 0; kk < 2; ++kk)
            af[0][kk] = *(const bf16x8*)((const char*)sA + b * 8192 + aRd[kk]);
#pragma unroll
        for (int nf = 0; nf < 3; ++nf)
#pragma unroll
            for (int kk = 0; kk < 2; ++kk)
                bfr[nf][kk] = *(const bf16x8*)((const char*)sB + b * 24576 +
                                               bRd[kk] + nf * 2048);
        __builtin_amdgcn_sched_barrier(0);     // pin issue order for lgkm(2)
        // group 2 reads: af[1] (2)
#pragma unroll
        for (int kk = 0; kk < 2; ++kk)
            af[1][kk] = *(const bf16x8*)((const char*)sA + b * 8192 + aRd[kk] + 2048);
        __builtin_amdgcn_sched_barrier(0);

        asm volatile("s_waitcnt lgkmcnt(2)" ::: "memory");   // group 1 done
        __builtin_amdgcn_sched_barrier(0);
        __builtin_amdgcn_s_setprio(1);
#pragma unroll
        for (int nf = 0; nf < 3; ++nf)
#pragma unroll
            for (int kk = 0; kk < 2; ++kk)
                acc[0][nf] = __builtin_amdgcn_mfma_f32_16x16x32_bf16(
                    af[0][kk], bfr[nf][kk], acc[0][nf], 0, 0, 0);
        __builtin_amdgcn_sched_barrier(0);
        asm volatile("s_waitcnt lgkmcnt(0)" ::: "memory");   // group 2 done
        __builtin_amdgcn_sched_barrier(0);
#pragma unroll
        for (int nf = 0; nf < 3; ++nf)
#pragma unroll
            for (int kk = 0; kk < 2; ++kk)
                acc[1][nf] = __builtin_amdgcn_mfma_f32_16x16x32_bf16(
                    af[1][kk], bfr[nf][kk], acc[1][nf], 0, 0, 0);
        __builtin_amdgcn_s_setprio(0);
        __builtin_amdgcn_sched_barrier(0);
        asm volatile("s_waitcnt vmcnt(0)" ::: "memory");
    }
#undef STA64
#undef STB64

    const int rowBase = m0 + wm + quad * 4;
    const int colBase = n0 + wn + l15;
#pragma unroll
    for (int nf = 0; nf < 3; ++nf) {
        const int col = colBase + nf * 16;
        const float bv = BIAS ? bias[col] : 0.0f;
#pragma unroll
        for (int mf = 0; mf < 2; ++mf) {
            const int row = rowBase + mf * 16;
#pragma unroll
            for (int r = 0; r < 4; ++r)
                C[(size_t)(row + r) * ldc + col] = (CT)(acc[mf][nf][r] + bv);
        }
    }
}

// ---------------------------------------------------------------------------
// QKNorm (fp32 RMS over head_dim=128) + RoPE + rearrange.
//  qkv [L][9216] bf16 -> Qh/Kh [24][2048][128] (normed+roped), Vt [24][128][2048].
// ---------------------------------------------------------------------------
__global__ __launch_bounds__(256)
void qk_rope_rearrange(const bf16* __restrict__ qkv, const float* __restrict__ pe,
                       const float* __restrict__ qs, const float* __restrict__ ks,
                       bf16* __restrict__ Qh, bf16* __restrict__ Kh, bf16* __restrict__ Vt)
{
    const int lane = threadIdx.x & 63;
    const int wid  = threadIdx.x >> 6;
    const int idx  = blockIdx.x * 4 + wid;     // = h*2048 + l
    const int h = idx >> 11;
    const int l = idx & 2047;

    const size_t rowb = (size_t)l * 9216 + h * 128 + 2 * lane;
    const float q0 = (float)qkv[rowb];
    const float q1 = (float)qkv[rowb + 1];
    const float k0 = (float)qkv[rowb + 3072];
    const float k1 = (float)qkv[rowb + 3073];
    const bf16  v0 = qkv[rowb + 6144];
    const bf16  v1 = qkv[rowb + 6145];

    float ssq = q0 * q0 + q1 * q1;
    float ssk = k0 * k0 + k1 * k1;
#pragma unroll
    for (int off = 1; off < 64; off <<= 1) {
        ssq += __shfl_xor(ssq, off);
        ssk += __shfl_xor(ssk, off);
    }
    const float rq = rsqrtf(ssq * (1.0f / 128.0f) + 1e-6f);
    const float rk = rsqrtf(ssk * (1.0f / 128.0f) + 1e-6f);

    const float s0q = qs[2 * lane], s1q = qs[2 * lane + 1];
    const float s0k = ks[2 * lane], s1k = ks[2 * lane + 1];

    const float qn0 = (q0 * rq) * s0q;
    const float qn1 = (q1 * rq) * s1q;
    const float kn0 = (k0 * rk) * s0k;
    const float kn1 = (k1 * rk) * s1k;

    const float* pp = pe + ((size_t)l * 64 + lane) * 4;
    const float p00 = pp[0], p01 = pp[1];
    const float p10 = pp[2], p11 = pp[3];

    const bf16 qo0 = (bf16)(p00 * qn0 + p01 * qn1);
    const bf16 qo1 = (bf16)(p10 * qn0 + p11 * qn1);
    const bf16 ko0 = (bf16)(p00 * kn0 + p01 * kn1);
    const bf16 ko1 = (bf16)(p10 * kn0 + p11 * kn1);

    const size_t ob = ((size_t)h * 2048 + l) * 128 + 2 * lane;
    Qh[ob] = qo0; Qh[ob + 1] = qo1;
    Kh[ob] = ko0; Kh[ob + 1] = ko1;

    const size_t vb = ((size_t)h * 128 + 2 * lane) * 2048 + l;
    Vt[vb]        = v0;
    Vt[vb + 2048] = v1;
}

// ---------------------------------------------------------------------------
// Flash attention v3. Block = 4 waves x 16 q-rows = 64 q; kv-steps of 64.
//  - K AND V staged via async global_load_lds into XOR-swizzled LDS tiles;
//    both double-buffered -> ONE barrier per step; DMA overlaps compute.
//  - No-max softmax: p = exp(s/sqrt(d)); row-sum via 2 MFMAs vs ones.
//  - setprio(1) wraps the MFMA clusters (T5: attn-proven +4-7%, m191).
// ---------------------------------------------------------------------------
__global__ __launch_bounds__(256, 2)
void flash_attn(const bf16* __restrict__ Qh, const bf16* __restrict__ Kh,
                const bf16* __restrict__ Vt, bf16* __restrict__ AO)
{
    __shared__ bf16 sK[2 * 64 * 128];  // [kv][d] swizzled, dbuf, 32 KB
    __shared__ bf16 sV[2 * 128 * 64];  // [d][kv] swizzled, dbuf, 32 KB
    __shared__ bf16 sP[4 * 16 * 72];   // per-wave P [q][kv], stride 72

    const int tid   = threadIdx.x;
    const int lane  = tid & 63;
    const int wid   = tid >> 6;
    const int h     = blockIdx.y;
    const int qw    = blockIdx.x * 64 + wid * 16;
    const int l15   = lane & 15;
    const int quad  = lane >> 4;
    const int quad8 = quad * 8;

    const bf16* Kbase = Kh + (size_t)h * 2048 * 128;
    const bf16* Vbase = Vt + (size_t)h * 128 * 2048;

    bf16x8 aq[4];
    {
        const bf16* qp = Qh + ((size_t)h * 2048 + qw + l15) * 128 + quad8;
#pragma unroll
        for (int ki = 0; ki < 4; ++ki) aq[ki] = *(const bf16x8*)(qp + ki * 32);
    }

    bf16x8 ones;
#pragma unroll
    for (int i = 0; i < 8; ++i) ones[i] = (bf16)1.0f;

    f32x4 o[8] = {};
    f32x4 lacc = {};

    bf16* sPw = sP + wid * (16 * 72);
    const int slotbase = wid * 64;

#define STAGE_K(kv, buf)                                                         \
    {                                                                            \
        bf16* kb = sK + (buf) * (64 * 128);                                      \
        _Pragma("unroll")                                                        \
        for (int t = 0; t < 4; ++t) {                                            \
            const int sb   = t * 256 + slotbase;                                 \
            const int slot = sb + lane;                                          \
            const int r    = slot >> 4;                                          \
            const int cg   = (slot & 15) ^ (r & 7);                              \
            LDS_LOAD16(Kbase + (size_t)((kv) + r) * 128 + cg * 8, kb + sb * 8);  \
        }                                                                        \
    }
#define STAGE_V(kv, buf)                                                         \
    {                                                                            \
        bf16* vb = sV + (buf) * (128 * 64);                                      \
        _Pragma("unroll")                                                        \
        for (int t = 0; t < 4; ++t) {                                            \
            const int sb   = t * 256 + slotbase;                                 \
            const int slot = sb + lane;                                          \
            const int r    = slot >> 3;                                          \
            const int cg   = (slot & 7) ^ (r & 7);                               \
            LDS_LOAD16(Vbase + (size_t)r * 2048 + (kv) + cg * 8, vb + sb * 8);   \
        }                                                                        \
    }

    STAGE_K(0, 0);
    STAGE_V(0, 0);

    for (int s = 0; s < 32; ++s) {
        __syncthreads();
        if (s < 31) {
            STAGE_K((s + 1) * 64, (s + 1) & 1);
            STAGE_V((s + 1) * 64, (s + 1) & 1);
        }

        const bf16* kb = sK + (s & 1) * (64 * 128);
        const bf16* vb = sV + (s & 1) * (128 * 64);

        // S = Q K^T  (16 MFMA), swizzled sK reads
        f32x4 sc[4];
        __builtin_amdgcn_s_setprio(1);
#pragma unroll
        for (int nt = 0; nt < 4; ++nt) {
            f32x4 t = {};
            const int row = nt * 16 + l15;
#pragma unroll
            for (int ki = 0; ki < 4; ++ki) {
                const int pcg = (4 * ki + quad) ^ (l15 & 7);
                bf16x8 bk = *(const bf16x8*)(kb + row * 128 + pcg * 8);
                t = __builtin_amdgcn_mfma_f32_16x16x32_bf16(aq[ki], bk, t, 0, 0, 0);
            }
            sc[nt] = t;
        }
        __builtin_amdgcn_s_setprio(0);

        // p = exp(s * scale); write P to LDS (C-layout -> A-layout transform)
#pragma unroll
        for (int r = 0; r < 4; ++r) {
            const float scl = 0.08838834764831845f;   // 1/sqrt(128)
            bf16* pw = sPw + (quad * 4 + r) * 72 + l15;
            pw[0]  = (bf16)__expf(sc[0][r] * scl);
            pw[16] = (bf16)__expf(sc[1][r] * scl);
            pw[32] = (bf16)__expf(sc[2][r] * scl);
            pw[48] = (bf16)__expf(sc[3][r] * scl);
        }

        // PV (16 MFMA, V from swizzled sV) + row-sum l (2 MFMA vs ones)
        __builtin_amdgcn_s_setprio(1);
#pragma unroll
        for (int kk = 0; kk < 2; ++kk) {
            bf16x8 pa = *(const bf16x8*)(sPw + l15 * 72 + kk * 32 + quad8);
            lacc = __builtin_amdgcn_mfma_f32_16x16x32_bf16(pa, ones, lacc, 0, 0, 0);
#pragma unroll
            for (int dt = 0; dt < 8; ++dt) {
                const int row = dt * 16 + l15;
                const int pcg = (kk * 4 + quad) ^ (l15 & 7);
                bf16x8 bv = *(const bf16x8*)(vb + row * 64 + pcg * 8);
                o[dt] = __builtin_amdgcn_mfma_f32_16x16x32_bf16(pa, bv, o[dt], 0, 0, 0);
            }
        }
        __builtin_amdgcn_s_setprio(0);
    }
#undef STAGE_K
#undef STAGE_V

#pragma unroll
    for (int r = 0; r < 4; ++r) {
        const float inv = 1.0f / lacc[r];
        const size_t row = qw + quad * 4 + r;
        bf16* op = AO + row * 3072 + h * 128 + l15;
#pragma unroll
        for (int dt = 0; dt < 8; ++dt) op[dt * 16] = (bf16)(o[dt][r] * inv);
    }
}

// ---------------------------------------------------------------------------
extern "C" void kernel_launch(void* const* d_in, const int* in_sizes, int n_in,
                              void* d_out, int out_size, void* d_ws, size_t ws_size,
                              hipStream_t stream)
{
    (void)in_sizes; (void)n_in; (void)out_size;

    const float* x      = (const float*)d_in[0];
    const float* pe     = (const float*)d_in[1];
    const float* w_qkv  = (const float*)d_in[2];
    const float* w_proj = (const float*)d_in[3];
    const float* b_proj = (const float*)d_in[4];
    const float* q_s    = (const float*)d_in[5];
    const float* k_s    = (const float*)d_in[6];
    float* out = (float*)d_out;

    const size_t NEED_BIG = ((size_t)6291456 + 28311552 + 18874368 + 6291456) * 2; // 119.5 MB

    if (ws_size >= NEED_BIG) {
        // single-launch QKV path
        bf16* xb  = (bf16*)d_ws;                  //  6291456  x bf16
        bf16* wb  = xb + (size_t)6291456;         // 28311552  w_qkv bf16
        bf16* qkv = wb + (size_t)28311552;        // 18874368  [2048][9216]
        bf16* Vt  = qkv + (size_t)18874368;       //  6291456  [24][128][2048]
        bf16* Qh  = xb;                           // alias after GEMM
        bf16* Kh  = wb;                           // alias after GEMM
        bf16* wpb = qkv;                          // alias after rearrange
        bf16* AO  = qkv + (size_t)9437184;

        f32_to_bf16<<<dim3(3072),  256, 0, stream>>>(x,     xb, 786432);
        f32_to_bf16<<<dim3(13824), 256, 0, stream>>>(w_qkv, wb, 3538944);
        // 128x192 GEMM @ 2 blocks/CU: grid 48x16 = 768 blocks = exactly 3/CU
        gemm128_bt<0, bf16><<<dim3(48, 16), 512, 0, stream>>>(xb, wb, nullptr, qkv, 3072, 9216);
        qk_rope_rearrange<<<dim3(12288), 256, 0, stream>>>(qkv, pe, q_s, k_s, Qh, Kh, Vt);
        f32_to_bf16<<<dim3(4608), 256, 0, stream>>>(w_proj, wpb, 1179648);
        flash_attn<<<dim3(32, 24), 256, 0, stream>>>(Qh, Kh, Vt, AO);
        // 64x192 proj GEMM @ 2 blocks/CU: grid 16x32 = 512 blocks = exactly 2/CU
        gemm64_bt<1, float><<<dim3(16, 32), 512, 0, stream>>>(AO, wpb, b_proj, out, 3072, 3072);
    } else {
        // chunked fallback (78.6 MB peak)
        bf16* xb  = (bf16*)d_ws;
        bf16* wb  = xb + (size_t)6291456;
        bf16* qkv = wb + (size_t)9437184;
        bf16* Vt  = qkv + (size_t)18874368;
        bf16* Qh  = xb;
        bf16* Kh  = wb;
        bf16* wpb = qkv;
        bf16* AO  = qkv + (size_t)9437184;

        f32_to_bf16<<<dim3(3072), 256, 0, stream>>>(x, xb, 786432);
        for (int c = 0; c < 3; ++c) {
            f32_to_bf16<<<dim3(4608), 256, 0, stream>>>(w_qkv + (size_t)c * 9437184, wb, 1179648);
            gemm_bt<0, bf16><<<dim3(24, 16), 256, 0, stream>>>(xb, wb, nullptr, qkv + c * 3072, 3072, 9216);
        }
        qk_rope_rearrange<<<dim3(12288), 256, 0, stream>>>(qkv, pe, q_s, k_s, Qh, Kh, Vt);
        f32_to_bf16<<<dim3(4608), 256, 0, stream>>>(w_proj, wpb, 1179648);
        flash_attn<<<dim3(32, 24), 256, 0, stream>>>(Qh, Kh, Vt, AO);
        gemm64_bt<1, float><<<dim3(16, 32), 512, 0, stream>>>(AO, wpb, b_proj, out, 3072, 3072);
    }
}